// Round 2
// baseline (23755.917 us; speedup 1.0000x reference)
//
#include <hip/hip_runtime.h>
#include <math.h>

#define H 2048
#define S 8192
#define RPB 8              // hidden rows per block
#define NBLK (H / RPB)     // 256 blocks = 256 CUs
#define PW16 (H / 4)       // 512 packed (4-row) 16B words per parity buffer
#define NREP 2             // hvt replicas (contention relief)
// hvt layout (as float4): [rep][parity][PW16] = 2*2*512*16B = 32 KB ws

typedef float f32x4 __attribute__((ext_vector_type(4)));
typedef unsigned int u32x4 __attribute__((ext_vector_type(4)));

// ---------------------------------------------------------------------------
// GEMM: U[t][j] = sum_k X[t][k] * Wxh[j][k]  (unchanged; not the bottleneck)
// ---------------------------------------------------------------------------
__global__ __launch_bounds__(256) void gemm_xw(const float* __restrict__ X,
                                               const float* __restrict__ W,
                                               float* __restrict__ U) {
    __shared__ float As[16][64];
    __shared__ float Bs[16][64];
    const int tid = threadIdx.x;
    const int t0 = blockIdx.x * 64;
    const int j0 = blockIdx.y * 64;
    const int tx = tid & 15, ty = tid >> 4;

    float acc[4][4] = {};
    const int lr = tid >> 2;
    const int lk = (tid & 3) * 4;

    for (int k0 = 0; k0 < H; k0 += 16) {
        float4 a = *(const float4*)&X[(size_t)(t0 + lr) * H + k0 + lk];
        float4 b = *(const float4*)&W[(size_t)(j0 + lr) * H + k0 + lk];
        As[lk + 0][lr] = a.x; As[lk + 1][lr] = a.y; As[lk + 2][lr] = a.z; As[lk + 3][lr] = a.w;
        Bs[lk + 0][lr] = b.x; Bs[lk + 1][lr] = b.y; Bs[lk + 2][lr] = b.z; Bs[lk + 3][lr] = b.w;
        __syncthreads();
#pragma unroll
        for (int kk = 0; kk < 16; ++kk) {
            float4 av = *(const float4*)&As[kk][ty * 4];
            float4 bv = *(const float4*)&Bs[kk][tx * 4];
            float aa[4] = {av.x, av.y, av.z, av.w};
            float bb[4] = {bv.x, bv.y, bv.z, bv.w};
#pragma unroll
            for (int i = 0; i < 4; ++i)
#pragma unroll
                for (int j = 0; j < 4; ++j)
                    acc[i][j] += aa[i] * bb[j];
        }
        __syncthreads();
    }
#pragma unroll
    for (int i = 0; i < 4; ++i) {
        float4 v = {acc[i][0], acc[i][1], acc[i][2], acc[i][3]};
        *(float4*)&U[(size_t)(t0 + ty * 4 + i) * H + j0 + tx * 4] = v;
    }
}

// ---------------------------------------------------------------------------
// Init: every 4B of hvt gets value 0.0f with LSB = parity-of-buffer.
// Parity-0 buffers (used at t=0, expected epoch 0): 0x0 -> h0 = 0, matches.
// Parity-1 buffers: LSB 1 mismatches t=1's expected epoch 0 -> poisoned.
// ---------------------------------------------------------------------------
__global__ void init_ws(unsigned int* __restrict__ w) {
    int i = blockIdx.x * blockDim.x + threadIdx.x;
    if (i < NREP * 2 * PW16 * 4) w[i] = (i >> 11) & 1u;   // (word>>9)&1 == parity
}

// ---------------------------------------------------------------------------
// Agent-scope (sc1: L2-bypass, LLC-coherent) 16B load/store helpers.
// Per-4B epoch LSBs make any tearing harmless; sc1 matches the LLVM mapping
// of relaxed agent-scope atomics on gfx94x/gfx950.
// ---------------------------------------------------------------------------
__device__ inline u32x4 ld16_sc1(const void* p) {
    u32x4 r;
    asm volatile("global_load_dwordx4 %0, %1, off sc1\n\t"
                 "s_waitcnt vmcnt(0)"
                 : "=&v"(r) : "v"(p) : "memory");
    return r;
}
__device__ inline void ld16x2_sc1(const void* p0, const void* p1, u32x4& a, u32x4& b) {
    asm volatile("global_load_dwordx4 %0, %2, off sc1\n\t"
                 "global_load_dwordx4 %1, %3, off sc1\n\t"
                 "s_waitcnt vmcnt(0)"
                 : "=&v"(a), "=&v"(b) : "v"(p0), "v"(p1) : "memory");
}
__device__ inline void st16_sc1(void* p, u32x4 v) {
    asm volatile("global_store_dwordx4 %0, %1, off sc1" :: "v"(p), "v"(v) : "memory");
}

// ---------------------------------------------------------------------------
// Persistent recurrent kernel, pure data-flow sync.
//  - W_hh fragment in 64 VGPRs/thread (8 rows x the 8 h-columns it polls).
//  - Poll: 2 x 16B sc1 loads/thread/round over replica (blockIdx&1); FMA each
//    4-row group into acc[8] on arrival (matvec hides under the wait).
//  - Publish: one 16B store per 4 rows per replica — 4-value groups become
//    visible atomically, and per-4B epoch LSB ((t>>1)&1) disambiguates the
//    2-step slot reuse. Skew<=1-step dataflow argument unchanged.
//  - Tail: folding butterfly (10 shfls, depth 6) -> 1 row/lane, LDS combine
//    across 4 waves (one __syncthreads), tanh, shfl-gather, publish.
//  - Fallback: if sc1 polling ever stalls 512 rounds, switch (sticky) to
//    __hip_atomic_load 8B polling — correctness insurance, normally dead.
// ---------------------------------------------------------------------------
__global__ __launch_bounds__(256) void rnn_recur(float* __restrict__ out,
                                                 const float* __restrict__ Whh,
                                                 const float* __restrict__ bias,
                                                 unsigned long long* __restrict__ hvt) {
    __shared__ __align__(16) float red[2][RPB][4];   // [parity][row][wave]
    const int tid = threadIdx.x;
    const int r0 = blockIdx.x * RPB;
    const int lane = tid & 63;
    const int wid = tid >> 6;

    // W fragment: wv[j][i] = W[r0+j][4*(i*256+tid) .. +3]  (coalesced 16B/lane)
    float4 wv[RPB][2];
#pragma unroll
    for (int j = 0; j < RPB; ++j)
#pragma unroll
        for (int i = 0; i < 2; ++i)
            wv[j][i] = *(const float4*)&Whh[(size_t)(r0 + j) * H + 4 * (i * 256 + tid)];

    const float bb = bias[r0 + (tid & 7)];
    f32x4* const hbase = (f32x4*)hvt;
    int fb = 0;   // sticky fallback flag

    for (int t = 0; t < S; ++t) {
        // Prefetch this step's U value (own row; latency hides under poll).
        float u_val = out[(size_t)t * H + r0 + (tid & 7)];

        const unsigned int ep = ((unsigned int)t >> 1) & 1u;
        const f32x4* hb = hbase + (size_t)(blockIdx.x & 1) * (2 * PW16) +
                          (size_t)(t & 1) * PW16;
        float acc[RPB] = {};
        unsigned int pend = 3u;
        int spin = 0;

        while (pend && !fb) {
            u32x4 va, vb;
            if (pend == 3u)      ld16x2_sc1(hb + tid, hb + 256 + tid, va, vb);
            else if (pend == 1u) va = ld16_sc1(hb + tid);
            else                 vb = ld16_sc1(hb + 256 + tid);
            if (pend & 1u) {
                if ((((va.x ^ ep) | (va.y ^ ep) | (va.z ^ ep) | (va.w ^ ep)) & 1u) == 0u) {
                    const float h0 = __uint_as_float(va.x), h1 = __uint_as_float(va.y);
                    const float h2 = __uint_as_float(va.z), h3 = __uint_as_float(va.w);
#pragma unroll
                    for (int j = 0; j < RPB; ++j)
                        acc[j] += wv[j][0].x * h0 + wv[j][0].y * h1 +
                                  wv[j][0].z * h2 + wv[j][0].w * h3;
                    pend &= ~1u;
                }
            }
            if (pend & 2u) {
                if ((((vb.x ^ ep) | (vb.y ^ ep) | (vb.z ^ ep) | (vb.w ^ ep)) & 1u) == 0u) {
                    const float h0 = __uint_as_float(vb.x), h1 = __uint_as_float(vb.y);
                    const float h2 = __uint_as_float(vb.z), h3 = __uint_as_float(vb.w);
#pragma unroll
                    for (int j = 0; j < RPB; ++j)
                        acc[j] += wv[j][1].x * h0 + wv[j][1].y * h1 +
                                  wv[j][1].z * h2 + wv[j][1].w * h3;
                    pend &= ~2u;
                }
            }
            if (pend) {
                __builtin_amdgcn_s_sleep(1);
                if (++spin > 512) fb = 1;   // sc1 insurance (normally never)
            }
        }
        // Fallback / remainder path: known-good 8B agent atomics.
        while (pend) {
#pragma unroll
            for (int i = 0; i < 2; ++i)
                if (pend & (1u << i)) {
                    const unsigned long long* q =
                        (const unsigned long long*)(hb + i * 256 + tid);
                    unsigned long long lo = __hip_atomic_load(q, __ATOMIC_RELAXED,
                                                              __HIP_MEMORY_SCOPE_AGENT);
                    unsigned long long hi = __hip_atomic_load(q + 1, __ATOMIC_RELAXED,
                                                              __HIP_MEMORY_SCOPE_AGENT);
                    u32x4 v; v.x = (unsigned int)lo; v.y = (unsigned int)(lo >> 32);
                    v.z = (unsigned int)hi; v.w = (unsigned int)(hi >> 32);
                    if ((((v.x ^ ep) | (v.y ^ ep) | (v.z ^ ep) | (v.w ^ ep)) & 1u) == 0u) {
                        const float h0 = __uint_as_float(v.x), h1 = __uint_as_float(v.y);
                        const float h2 = __uint_as_float(v.z), h3 = __uint_as_float(v.w);
#pragma unroll
                        for (int j = 0; j < RPB; ++j)
                            acc[j] += wv[j][i].x * h0 + wv[j][i].y * h1 +
                                      wv[j][i].z * h2 + wv[j][i].w * h3;
                        pend &= ~(1u << i);
                    }
                }
            if (pend) __builtin_amdgcn_s_sleep(1);
        }

        // Folding butterfly: 8 rows x 64 lanes -> 1 row/lane (10 shfls, depth 6).
#pragma unroll
        for (int j = 0; j < 4; ++j) {
            float s = (lane & 1) ? acc[j] : acc[j + 4];
            float r = __shfl_xor(s, 1, 64);
            acc[j] = ((lane & 1) ? acc[j + 4] : acc[j]) + r;
        }
#pragma unroll
        for (int j = 0; j < 2; ++j) {
            float s = (lane & 2) ? acc[j] : acc[j + 2];
            float r = __shfl_xor(s, 2, 64);
            acc[j] = ((lane & 2) ? acc[j + 2] : acc[j]) + r;
        }
        {
            float s = (lane & 4) ? acc[0] : acc[1];
            float r = __shfl_xor(s, 4, 64);
            acc[0] = ((lane & 4) ? acc[1] : acc[0]) + r;
        }
#pragma unroll
        for (int m = 8; m <= 32; m <<= 1)
            acc[0] += __shfl_xor(acc[0], m, 64);
        // lane holds row ((lane&1)<<2)|(lane&2)|((lane&4)>>2), bit-reverse of lane&7
        if (lane < 8)
            red[t & 1][((lane & 1) << 2) | (lane & 2) | ((lane & 4) >> 2)][wid] = acc[0];
        __syncthreads();

        if (tid < 8) {
            const float4 r4 = *(const float4*)red[t & 1][tid];
            const float val = tanhf(r4.x + r4.y + r4.z + r4.w + u_val + bb);
            out[(size_t)t * H + r0 + tid] = val;                  // overwrite U with h_t
            if (t == S - 1) out[(size_t)S * H + r0 + tid] = val;  // h_T
            // Gather 4 adjacent rows into one 16B word (single-store visibility).
            const float p0 = __shfl(val, (int)(tid & 4) | 0, 64);
            const float p1 = __shfl(val, (int)(tid & 4) | 1, 64);
            const float p2 = __shfl(val, (int)(tid & 4) | 2, 64);
            const float p3 = __shfl(val, (int)(tid & 4) | 3, 64);
            if ((tid & 3) == 0) {
                const unsigned int e2 = (((unsigned int)(t + 1)) >> 1) & 1u;
                u32x4 pk;
                pk.x = (__float_as_uint(p0) & ~1u) | e2;
                pk.y = (__float_as_uint(p1) & ~1u) | e2;
                pk.z = (__float_as_uint(p2) & ~1u) | e2;
                pk.w = (__float_as_uint(p3) & ~1u) | e2;
                const int widx = (r0 >> 2) + (tid >> 2);
                const size_t par = (size_t)((t + 1) & 1) * PW16;
#pragma unroll
                for (int rep = 0; rep < NREP; ++rep)
                    st16_sc1(hbase + (size_t)rep * (2 * PW16) + par + widx, pk);
            }
        }
        // No trailing barrier: next step's partials go to red[(t+1)&1]; reuse
        // of red[t&1] at t+2 is gated by the global dataflow (skew <= 1 step).
    }
}

extern "C" void kernel_launch(void* const* d_in, const int* in_sizes, int n_in,
                              void* d_out, int out_size, void* d_ws, size_t ws_size,
                              hipStream_t stream) {
    const float* X    = (const float*)d_in[0];  // (8192, 2048)
    const float* Wxh  = (const float*)d_in[1];  // (2048, 2048)
    const float* Whh  = (const float*)d_in[2];  // (2048, 2048)
    const float* bias = (const float*)d_in[3];  // (2048,)
    float* out = (float*)d_out;
    unsigned long long* hvt = (unsigned long long*)d_ws;   // 32 KB: [2 rep][2 par][512 x16B]

    // Phase 0: init replicated packed h buffers.
    init_ws<<<(NREP * 2 * PW16 * 4 + 255) / 256, 256, 0, stream>>>((unsigned int*)hvt);

    // Phase 1: U = X @ Wxh^T into out[0 .. S*H)
    dim3 ggrid(S / 64, H / 64);
    gemm_xw<<<ggrid, 256, 0, stream>>>(X, Wxh, out);

    // Phase 2: sequential recurrence (cooperative launch; data-flow sync).
    void* args[] = {(void*)&out, (void*)&Whh, (void*)&bias, (void*)&hvt};
    hipLaunchCooperativeKernel((void*)rnn_recur, dim3(NBLK), dim3(256), args, 0, stream);
}